// Round 2
// baseline (178.892 us; speedup 1.0000x reference)
//
#include <hip/hip_runtime.h>

// ts_corr: X (16384, 15, 100) f32 -> corr (16384, 105, 10) f32
// D = 10, STRIDE = 10 -> w = 10 non-overlapping windows.
// corr[b, p(i,j), w] = cov_ij / (std_i * std_j)
//   cov_ij = sum_d c_i[d] c_j[d] / D        (D = 10)
//   std_i  = sqrt(sum_d c_i[d]^2 / (D-1))   (D-1 = 9)

#define NB    16384
#define NSER  15
#define TLEN  100
#define DWIN  10
#define WCNT  10
#define NPAIR 105   // 15*14/2

__global__ __launch_bounds__(64) void ts_corr_kernel(const float* __restrict__ X,
                                                     float* __restrict__ out) {
    const int task = blockIdx.x * 64 + threadIdx.x;   // grid sized exactly
    const int b = task / WCNT;
    const int w = task % WCNT;

    const float* Xb = X + (size_t)b * (NSER * TLEN) + w * DWIN;

    // Load 15 windows of 10 floats. All offsets are multiples of 40B -> 8B aligned.
    float win[NSER][DWIN];
    #pragma unroll
    for (int i = 0; i < NSER; ++i) {
        const float2* p2 = reinterpret_cast<const float2*>(Xb + i * TLEN);
        #pragma unroll
        for (int k = 0; k < 5; ++k) {
            float2 v = p2[k];
            win[i][2 * k]     = v.x;
            win[i][2 * k + 1] = v.y;
        }
    }

    // Center each window in place; compute 1/std.
    float istd[NSER];
    #pragma unroll
    for (int i = 0; i < NSER; ++i) {
        float s = 0.f;
        #pragma unroll
        for (int d = 0; d < DWIN; ++d) s += win[i][d];
        const float m = s * (1.0f / DWIN);
        float sq = 0.f;
        #pragma unroll
        for (int d = 0; d < DWIN; ++d) {
            const float c = win[i][d] - m;
            win[i][d] = c;
            sq += c * c;
        }
        istd[i] = rsqrtf(sq * (1.0f / (DWIN - 1)));
    }

    // 105 pair dot products, stored in triu_indices(15, k=1) order.
    float* o = out + (size_t)b * (NPAIR * WCNT) + w;
    int p = 0;
    #pragma unroll
    for (int i = 0; i < NSER; ++i) {
        #pragma unroll
        for (int j = i + 1; j < NSER; ++j) {
            float dot = 0.f;
            #pragma unroll
            for (int d = 0; d < DWIN; ++d) dot += win[i][d] * win[j][d];
            o[(size_t)p * WCNT] = dot * (1.0f / DWIN) * istd[i] * istd[j];
            ++p;
        }
    }
}

extern "C" void kernel_launch(void* const* d_in, const int* in_sizes, int n_in,
                              void* d_out, int out_size, void* d_ws, size_t ws_size,
                              hipStream_t stream) {
    const float* X = (const float*)d_in[0];
    float* out = (float*)d_out;
    const int total = NB * WCNT;            // 163840 tasks
    const int block = 64;
    const int grid = (total + block - 1) / block;  // 2560 blocks, exact
    ts_corr_kernel<<<grid, block, 0, stream>>>(X, out);
}